// Round 5
// baseline (568.651 us; speedup 1.0000x reference)
//
#include <hip/hip_runtime.h>
#include <hip/hip_bf16.h>

#define B_      2048
#define R_      333
#define MAXI_   119
#define MAXO_   12
#define CONCAT_ 3325
#define E_      3328
#define TOTAL_  24696
#define HID_    1024
#define NREG_   300
#define NCLS_   180
#define EPS_    1e-5f
#define NSLOT_  128  // BN1 partial-stat slots (2048 rows / 16 rows-per-tile)
#define PSTR_   3328 // partial-stat stride
#define CHN_    49   // 512-col x chunks
#define CHW_    640  // staged width (512 + 128 overlap)
#define XSTR_   648  // LDS row stride (bf16): 16B-aligned rows (648%16==8 -> bank spread)

typedef __attribute__((ext_vector_type(8))) short bf16x8;
typedef __attribute__((ext_vector_type(4))) float f32x4;

static __device__ inline unsigned short f2bf_rne(float f) {
  unsigned u;
  __builtin_memcpy(&u, &f, 4);
  u += 0x7fff + ((u >> 16) & 1);     // round-nearest-even; inputs finite
  return (unsigned short)(u >> 16);
}

// ---------------- layout: ROI starts / reduced starts / 512-chunk tables ----------------
__global__ void layout_kernel(int* __restrict__ starts, int* __restrict__ red_starts,
                              int* __restrict__ chunk_first, int* __restrict__ chunk_cnt) {
  if (threadIdx.x == 0 && blockIdx.x == 0) {
    for (int c = 0; c < CHN_; ++c) { chunk_first[c] = 0; chunk_cnt[c] = 0; }
    int s = 0, rs = 0;
    for (int r = 0; r < R_; ++r) {
      starts[r] = s;
      red_starts[r] = rs;
      int c = s >> 9;
      if (chunk_cnt[c] == 0) chunk_first[c] = r;
      chunk_cnt[c]++;
      s += 30 + (7 * r) % 90;
      rs += (r == 332) ? 8 : (8 + r % 5);
    }
  }
}

// ---------------- f32 -> bf16 cast (vectorized) ----------------
__global__ __launch_bounds__(256) void cast_bf16_kernel(const float* __restrict__ src,
                                                        unsigned short* __restrict__ dst, int n4) {
  int i = blockIdx.x * 256 + threadIdx.x;
  if (i >= n4) return;
  float4 v = ((const float4*)src)[i];
  ushort4 o;
  o.x = f2bf_rne(v.x); o.y = f2bf_rne(v.y); o.z = f2bf_rne(v.z); o.w = f2bf_rne(v.w);
  ((ushort4*)dst)[i] = o;
}

// ---------------- pack enc_W into MFMA A-frag order, alignment shift baked in ----------
// Wpk[r][kc][lane][8]: lane holds W'[oc=lane&15][k' = kc*32+(lane>>4)*8+e] where
// W'[oc][k'] = enc_W[r][oc][k'-s], s = starts[r]&7 (zero outside [s, s+size)).
// Then y[oc,b] = sum_k' W'[oc,k'] * x[b, (start&~7)+k'] with all LDS reads 16B-aligned.
__global__ __launch_bounds__(256) void pack_w_kernel(const float* __restrict__ enc_W,
                                                     const int* __restrict__ starts,
                                                     unsigned short* __restrict__ Wpk) {
  int r = blockIdx.x;
  int tid = threadIdx.x;
  int kc = tid >> 6, lane = tid & 63;
  int size = 30 + (7 * r) % 90;
  int s8 = starts[r] & 7;
  int oc = lane & 15;
  int k0 = kc * 32 + (lane >> 4) * 8;
  unsigned short o[8];
#pragma unroll
  for (int e = 0; e < 8; ++e) {
    int k = k0 + e - s8;
    float v = 0.f;
    if (oc < MAXO_ && k >= 0 && k < size) v = enc_W[((size_t)r * MAXO_ + oc) * MAXI_ + k];
    o[e] = f2bf_rne(v);
  }
  unsigned short* dst = Wpk + ((size_t)r * 4 + kc) * 512 + lane * 8;
  *(ushort4*)dst = *(ushort4*)&o[0];
  *(ushort4*)(dst + 4) = *(ushort4*)&o[4];
}

// ---------------- ragged encoder: 8 dbuf'd 16-row tiles per block ----------------
// block = (chunk c of 512 cols, batch group of 128 rows). Stage x tile (16 rows x 640
// cols, f32->bf16, coalesced) into LDS buf, double-buffered across 8 tiles; per-ROI
// MFMA with 16B-aligned ds_read_b128 frags; fused BN1 partial stats.
__global__ __launch_bounds__(256) void encode_kernel(
    const float* __restrict__ x, const unsigned short* __restrict__ Wpk,
    const float* __restrict__ enc_b, const int* __restrict__ starts,
    const int* __restrict__ red_starts, const int* __restrict__ chunk_first,
    const int* __restrict__ chunk_cnt,
    float* __restrict__ yT, float* __restrict__ pS1, float* __restrict__ pS2) {
  __shared__ __align__(16) unsigned short xt[2][16][XSTR_];
  __shared__ float bb_lds[224];
  int c  = blockIdx.x;
  int bg = blockIdx.y;                 // 0..15, rows bg*128 .. +128
  int tid = threadIdx.x;
  int base = c << 9;
  int avail = TOTAL_ - base; if (avail > CHW_) avail = CHW_;
  int nv4 = avail >> 2;                // avail multiple of 4 (512-chunks; last = 120)
  int first = chunk_first[c], cnt = chunk_cnt[c];

  if (tid < cnt * MAXO_) bb_lds[tid] = enc_b[first * MAXO_ + tid];

  int srow = tid >> 4, j0 = tid & 15;

#define ESTAGE_(buf, t)                                                          \
  do {                                                                           \
    const float* src = x + (size_t)(bg * 128 + (t) * 16 + srow) * TOTAL_ + base; \
    for (int j = j0; j < 160; j += 16) {                                         \
      float4 v = {0.f, 0.f, 0.f, 0.f};                                           \
      if (j < nv4) v = *(const float4*)(src + j * 4);                            \
      ushort4 o;                                                                 \
      o.x = f2bf_rne(v.x); o.y = f2bf_rne(v.y);                                  \
      o.z = f2bf_rne(v.z); o.w = f2bf_rne(v.w);                                  \
      *(ushort4*)&xt[buf][srow][j * 4] = o;                                      \
    }                                                                            \
  } while (0)

  int wid = tid >> 6, lane = tid & 63;
  int lr = lane & 15, kg = lane >> 4;

  ESTAGE_(0, 0);
  __syncthreads();
  int cur = 0;
  for (int t = 0; t < 8; ++t) {
    if (t + 1 < 8) ESTAGE_(cur ^ 1, t + 1);       // loads fly under compute
    for (int ri = wid; ri < cnt; ri += 4) {
      int r = first + ri;
      int size = 30 + (7 * r) % 90;
      int red  = (r == 332) ? 8 : (8 + r % 5);
      int st   = starts[r];
      int s8   = st & 7;
      int ls8  = (st - base) & ~7;
      int rs   = red_starts[r];
      int nkc  = (s8 + size + 31) >> 5;

      f32x4 acc = {0.f, 0.f, 0.f, 0.f};
      const unsigned short* wp = Wpk + (size_t)r * 2048 + lane * 8;
      for (int kc = 0; kc < nkc; ++kc) {
        bf16x8 wf = *(const bf16x8*)(wp + kc * 512);
        bf16x8 xf = *(const bf16x8*)&xt[cur][lr][ls8 + kc * 32 + kg * 8];  // 16B-aligned
        acc = __builtin_amdgcn_mfma_f32_16x16x32_bf16(wf, xf, acc, 0, 0, 0);
      }
      // C layout: col = lane&15 = batch, row = kg*4+reg = oc
#pragma unroll
      for (int reg = 0; reg < 4; ++reg) {
        int oc = kg * 4 + reg;
        if (oc < red) {
          float v = acc[reg] + bb_lds[ri * MAXO_ + oc];
          yT[(size_t)(rs + oc) * B_ + bg * 128 + t * 16 + lr] = v;
          float a = v, s2 = v * v;
#pragma unroll
          for (int m = 1; m <= 8; m <<= 1) { a += __shfl_xor(a, m); s2 += __shfl_xor(s2, m); }
          if (lr == 0) {
            int slot = bg * 8 + t;
            pS1[slot * PSTR_ + rs + oc] = a;
            pS2[slot * PSTR_ + rs + oc] = s2;
          }
        }
      }
    }
    __syncthreads();                  // stage(t+1) ds_writes + compute(t) reads done
    cur ^= 1;
  }
#undef ESTAGE_
}

// ---------------- BN1 stats finalize (128 slot-partials -> mean/rstd) ----------------
__global__ __launch_bounds__(256) void bn1_stats_kernel(const float* __restrict__ pS1,
                                                        const float* __restrict__ pS2,
                                                        float* __restrict__ mean, float* __restrict__ rstd) {
  int c = blockIdx.x * 256 + threadIdx.x;
  if (c >= CONCAT_) return;
  float s = 0.f, s2 = 0.f;
  for (int i = 0; i < NSLOT_; ++i) { s += pS1[i * PSTR_ + c]; s2 += pS2[i * PSTR_ + c]; }
  float m = s / B_;
  float v = s2 / B_ - m * m;
  mean[c] = m;
  rstd[c] = rsqrtf(v + EPS_);
}

// ---------------- BN1 + LeakyReLU(0.3) + transpose + pad-col write (bf16) ----------------
__global__ __launch_bounds__(256) void bn1_transpose_kernel(
    const float* __restrict__ yT, const float* __restrict__ mean, const float* __restrict__ rstd,
    const float* __restrict__ g, const float* __restrict__ bb, unsigned short* __restrict__ Y) {
  __shared__ float tile[64][65];
  int c0 = blockIdx.x * 64, b0 = blockIdx.y * 64;
  int t = threadIdx.x;
  int bi = t & 63, ci0 = t >> 6;
  for (int ci = ci0; ci < 64; ci += 4) {
    int c = c0 + ci;
    float v = 0.f;
    if (c < CONCAT_) {
      v = (yT[(size_t)c * B_ + b0 + bi] - mean[c]) * rstd[c] * g[c] + bb[c];
      v = v > 0.f ? v : 0.3f * v;
    }
    tile[ci][bi] = v;
  }
  __syncthreads();
  int cj = t & 63, bj0 = t >> 6;
  for (int bj = bj0; bj < 64; bj += 4) {
    int c = c0 + cj;
    if (c < CONCAT_)
      Y[(size_t)(b0 + bj) * E_ + c + 1] = f2bf_rne(tile[cj][bj]);
  }
}

__global__ __launch_bounds__(256) void pad_zero_kernel(unsigned short* __restrict__ Y) {
  int i = blockIdx.x * 256 + threadIdx.x;
  if (i >= B_ * 3) return;
  int b = i / 3, which = i % 3;
  int c = (which == 0) ? 0 : ((which == 1) ? 3326 : 3327);
  Y[(size_t)b * E_ + c] = 0;
}

// ---------------- 128x64-tile dbuf bf16 MFMA GEMM (+optional split-K) ----------------
// C = A[M][K] @ W[N][K]^T (+bias if KS==1). Grid (N/64, M/128, KS). 4 waves 2x2,
// wave = 64x32 = 4x2 frags. BK=32, global_load_lds staging, prefetch-before-compute.
template <int KS, bool OUT_BF16>
__global__ __launch_bounds__(256) void gemm_lds_kernel(
    const unsigned short* __restrict__ A, const unsigned short* __restrict__ W,
    const float* __restrict__ bias, float* __restrict__ Cf, unsigned short* __restrict__ Cb,
    int M, int N, int K) {
  __shared__ unsigned short a_lds[2][128 * 32];   // 8KB each
  __shared__ unsigned short b_lds[2][64 * 32];    // 4KB each
  int tid = threadIdx.x;
  int wid = tid >> 6, lane = tid & 63;
  int wr = wid >> 1, wc = wid & 1;
  int row0 = blockIdx.y * 128, col0 = blockIdx.x * 64;
  int lr = lane & 15, kg = lane >> 4;
  int Klocal = K / KS;
  int kbase = blockIdx.z * Klocal;

  int srow = tid >> 2, sk = (tid & 3) * 8;
  const unsigned short* aptr0 = A + (size_t)(row0 + srow) * K + kbase + sk;
  const unsigned short* aptr1 = aptr0 + (size_t)64 * K;
  int bcol = col0 + srow; if (bcol > N - 1) bcol = N - 1;   // N-tail clamp (discarded)
  const unsigned short* bptr = W + (size_t)bcol * K + kbase + sk;

  f32x4 acc[4][2] = {};
  int nk = Klocal >> 5;

#define STAGE_(buf, kc)                                                                         \
  do {                                                                                          \
    __builtin_amdgcn_global_load_lds((const __attribute__((address_space(1))) void*)(aptr0 + (kc)), \
        (__attribute__((address_space(3))) void*)(&a_lds[buf][wid * 512]), 16, 0, 0);           \
    __builtin_amdgcn_global_load_lds((const __attribute__((address_space(1))) void*)(aptr1 + (kc)), \
        (__attribute__((address_space(3))) void*)(&a_lds[buf][2048 + wid * 512]), 16, 0, 0);    \
    __builtin_amdgcn_global_load_lds((const __attribute__((address_space(1))) void*)(bptr + (kc)),  \
        (__attribute__((address_space(3))) void*)(&b_lds[buf][wid * 512]), 16, 0, 0);           \
  } while (0)

  STAGE_(0, 0);
  __syncthreads();
  int cur = 0;
  for (int t = 0; t < nk; ++t) {
    if (t + 1 < nk) STAGE_(cur ^ 1, (t + 1) * 32);
    bf16x8 a[4], b[2];
#pragma unroll
    for (int f = 0; f < 4; ++f)
      a[f] = *(const bf16x8*)&a_lds[cur][(wr * 64 + f * 16 + lr) * 32 + kg * 8];
#pragma unroll
    for (int f = 0; f < 2; ++f)
      b[f] = *(const bf16x8*)&b_lds[cur][(wc * 32 + f * 16 + lr) * 32 + kg * 8];
#pragma unroll
    for (int i = 0; i < 4; ++i)
#pragma unroll
      for (int j = 0; j < 2; ++j)
        acc[i][j] = __builtin_amdgcn_mfma_f32_16x16x32_bf16(a[i], b[j], acc[i][j], 0, 0, 0);
    __syncthreads();
    cur ^= 1;
  }
#undef STAGE_

  // C/D: col = lane&15, row = (lane>>4)*4 + reg
#pragma unroll
  for (int j = 0; j < 2; ++j) {
    int ccol = col0 + wc * 32 + j * 16 + lr;
    if (ccol >= N) continue;
    float bv = (KS == 1) ? bias[ccol] : 0.f;
#pragma unroll
    for (int i = 0; i < 4; ++i) {
#pragma unroll
      for (int reg = 0; reg < 4; ++reg) {
        int crow = row0 + wr * 64 + i * 16 + kg * 4 + reg;
        float v = acc[i][j][reg] + bv;
        if (KS == 1) {
          if (OUT_BF16) Cb[(size_t)crow * N + ccol] = f2bf_rne(v);
          else          Cf[(size_t)crow * N + ccol] = v;
        } else {
          Cf[((size_t)blockIdx.z * M + crow) * N + ccol] = v;
        }
      }
    }
  }
}

// ---------------- split-K combine: sum partials + bias ----------------
__global__ __launch_bounds__(256) void combine_kernel(
    const float* __restrict__ part, const float* __restrict__ bias,
    float* __restrict__ out, int MN, int N, int KS) {
  int i = blockIdx.x * 256 + threadIdx.x;
  if (i >= MN) return;
  float s = bias[i % N];
  for (int z = 0; z < KS; ++z) s += part[(size_t)z * MN + i];
  out[i] = s;
}

// ---------------- BN2 stats over row-major Z (two-stage, deterministic) ----------------
__global__ __launch_bounds__(256) void colstats_partial_kernel(
    const float* __restrict__ Z, float* __restrict__ pS, float* __restrict__ pS2,
    int M, int C, int rowsPerBlock) {
  int c = blockIdx.x * 256 + threadIdx.x;
  if (c >= C) return;
  int r0 = blockIdx.y * rowsPerBlock;
  float s = 0.f, s2 = 0.f;
  for (int r = r0; r < r0 + rowsPerBlock; ++r) {
    float v = Z[(size_t)r * C + c];
    s += v; s2 = fmaf(v, v, s2);
  }
  pS[blockIdx.y * C + c] = s;
  pS2[blockIdx.y * C + c] = s2;
}

__global__ __launch_bounds__(256) void colstats_final_kernel(
    const float* __restrict__ pS, const float* __restrict__ pS2,
    float* __restrict__ mean, float* __restrict__ rstd, int C, int nrb, int M) {
  int c = blockIdx.x * 256 + threadIdx.x;
  if (c >= C) return;
  float s = 0.f, s2 = 0.f;
  for (int i = 0; i < nrb; ++i) { s += pS[i * C + c]; s2 += pS2[i * C + c]; }
  float m = s / M;
  float v = s2 / M - m * m;
  mean[c] = m;
  rstd[c] = rsqrtf(v + EPS_);
}

// ---------------- BN2 apply + LeakyReLU(0.1) -> bf16 ----------------
__global__ __launch_bounds__(256) void bn2_apply_kernel(
    const float* __restrict__ Z, const float* __restrict__ mean, const float* __restrict__ rstd,
    const float* __restrict__ g, const float* __restrict__ bb, unsigned short* __restrict__ R) {
  int i = blockIdx.x * 256 + threadIdx.x;
  int c = i & (HID_ - 1);
  float v = (Z[i] - mean[c]) * rstd[c] * g[c] + bb[c];
  v = v > 0.f ? v : 0.1f * v;
  R[i] = f2bf_rne(v);
}

// ---------------- classifier: y_pred = softmax(reg @ Wc^T + bc) ----------------
__global__ __launch_bounds__(256) void classifier_kernel(
    const float* __restrict__ reg, const float* __restrict__ Wc, const float* __restrict__ bc,
    float* __restrict__ ypred) {
  int b = blockIdx.x;
  __shared__ __align__(16) float rrow[NREG_];
  __shared__ float sl[256];
  int tid = threadIdx.x;
  for (int i = tid; i < NREG_; i += 256) rrow[i] = reg[(size_t)b * NREG_ + i];
  __syncthreads();
  float s = -1e30f;
  if (tid < NCLS_) {
    const float* w = Wc + (size_t)tid * NREG_;
    float acc = 0.f;
    for (int k = 0; k < NREG_; k += 4) {
      float4 wv = *(const float4*)(w + k);
      float4 rv = *(const float4*)(&rrow[k]);
      acc = fmaf(wv.x, rv.x, acc); acc = fmaf(wv.y, rv.y, acc);
      acc = fmaf(wv.z, rv.z, acc); acc = fmaf(wv.w, rv.w, acc);
    }
    s = acc + bc[tid];
  }
  sl[tid] = s;
  __syncthreads();
  for (int o = 128; o > 0; o >>= 1) {
    if (tid < o) sl[tid] = fmaxf(sl[tid], sl[tid + o]);
    __syncthreads();
  }
  float mx = sl[0];
  __syncthreads();
  float e = (tid < NCLS_) ? __expf(s - mx) : 0.f;
  sl[tid] = e;
  __syncthreads();
  for (int o = 128; o > 0; o >>= 1) {
    if (tid < o) sl[tid] += sl[tid + o];
    __syncthreads();
  }
  if (tid < NCLS_) ypred[(size_t)b * NCLS_ + tid] = e / sl[0];
}

// ---------------- host orchestration ----------------
extern "C" void kernel_launch(void* const* d_in, const int* in_sizes, int n_in,
                              void* d_out, int out_size, void* d_ws, size_t ws_size,
                              hipStream_t stream) {
  const float* x     = (const float*)d_in[0];
  const float* enc_W = (const float*)d_in[1];
  const float* enc_b = (const float*)d_in[2];
  const float* bn1_g = (const float*)d_in[3];
  const float* bn1_b = (const float*)d_in[4];
  const float* Wqkv  = (const float*)d_in[5];
  const float* bqkv  = (const float*)d_in[6];
  const float* Wo    = (const float*)d_in[7];
  const float* bo    = (const float*)d_in[8];
  const float* W1    = (const float*)d_in[9];
  const float* b1    = (const float*)d_in[10];
  const float* bn2_g = (const float*)d_in[11];
  const float* bn2_b = (const float*)d_in[12];
  const float* W2    = (const float*)d_in[13];
  const float* b2    = (const float*)d_in[14];
  const float* Wc    = (const float*)d_in[15];
  const float* bc    = (const float*)d_in[16];

  char* ws = (char*)d_ws;
  size_t off = 0;
  auto alloc = [&](size_t bytes) -> void* {
    void* p = ws + off;
    off += (bytes + 255) & ~(size_t)255;
    return p;
  };

  float*          yT     = (float*)alloc((size_t)CONCAT_ * B_ * 4);       // reused for Z
  float*          pS1b   = (float*)alloc((size_t)NSLOT_ * PSTR_ * 4);
  float*          pS2b   = (float*)alloc((size_t)NSLOT_ * PSTR_ * 4);
  float*          mean1  = (float*)alloc(CONCAT_ * 4);
  float*          rstd1  = (float*)alloc(CONCAT_ * 4);
  unsigned short* Ybf    = (unsigned short*)alloc((size_t)B_ * E_ * 2);   // reused for O
  unsigned short* Vbf    = (unsigned short*)alloc((size_t)B_ * E_ * 2);   // reused for R
  unsigned short* Wv_bf  = (unsigned short*)alloc((size_t)E_ * E_ * 2);
  unsigned short* Wo_bf  = (unsigned short*)alloc((size_t)E_ * E_ * 2);
  unsigned short* W1_bf  = (unsigned short*)alloc((size_t)HID_ * E_ * 2);
  unsigned short* W2_bf  = (unsigned short*)alloc((size_t)NREG_ * HID_ * 2);
  unsigned short* Wpk    = (unsigned short*)alloc((size_t)R_ * 2048 * 2);
  float*          Cpart  = (float*)alloc((size_t)2 * B_ * HID_ * 4);      // split-K partials
  float*          partS  = (float*)alloc(16 * HID_ * 4);
  float*          partS2 = (float*)alloc(16 * HID_ * 4);
  float*          mean2  = (float*)alloc(HID_ * 4);
  float*          rstd2  = (float*)alloc(HID_ * 4);
  int*            starts = (int*)alloc(R_ * 4);
  int*            redst  = (int*)alloc(R_ * 4);
  int*            chF    = (int*)alloc(CHN_ * 4);
  int*            chC    = (int*)alloc(CHN_ * 4);

  unsigned short* Obf = Ybf;
  float*          Z   = yT;
  unsigned short* Rbf = Vbf;

  layout_kernel<<<1, 1, 0, stream>>>(starts, redst, chF, chC);
  pack_w_kernel<<<R_, 256, 0, stream>>>(enc_W, starts, Wpk);

  int n4 = (E_ * E_) / 4;
  cast_bf16_kernel<<<(n4 + 255) / 256, 256, 0, stream>>>(Wqkv + (size_t)2 * E_ * E_, Wv_bf, n4);
  cast_bf16_kernel<<<(n4 + 255) / 256, 256, 0, stream>>>(Wo, Wo_bf, n4);
  n4 = (HID_ * E_) / 4;
  cast_bf16_kernel<<<(n4 + 255) / 256, 256, 0, stream>>>(W1, W1_bf, n4);
  n4 = (NREG_ * HID_) / 4;
  cast_bf16_kernel<<<(n4 + 255) / 256, 256, 0, stream>>>(W2, W2_bf, n4);

  encode_kernel<<<dim3(CHN_, B_ / 128), 256, 0, stream>>>(
      x, Wpk, enc_b, starts, redst, chF, chC, yT, pS1b, pS2b);
  bn1_stats_kernel<<<(CONCAT_ + 255) / 256, 256, 0, stream>>>(pS1b, pS2b, mean1, rstd1);
  bn1_transpose_kernel<<<dim3((CONCAT_ + 63) / 64, B_ / 64), 256, 0, stream>>>(
      yT, mean1, rstd1, bn1_g, bn1_b, Ybf);
  pad_zero_kernel<<<(B_ * 3 + 255) / 256, 256, 0, stream>>>(Ybf);

  // V = Y @ Wv^T + bv  (L=1 softmax == 1 -> attention output == V; q,k never needed)
  gemm_lds_kernel<1, true><<<dim3(E_ / 64, B_ / 128), 256, 0, stream>>>(
      Ybf, Wv_bf, bqkv + 2 * E_, nullptr, Vbf, B_, E_, E_);
  // O = V @ Wo^T + bo
  gemm_lds_kernel<1, true><<<dim3(E_ / 64, B_ / 128), 256, 0, stream>>>(
      Vbf, Wo_bf, bo, nullptr, Obf, B_, E_, E_);
  // Z = O @ W1^T + b1  (split-K=2 for parallelism: 512 blocks)
  gemm_lds_kernel<2, false><<<dim3(HID_ / 64, B_ / 128, 2), 256, 0, stream>>>(
      Obf, W1_bf, nullptr, Cpart, nullptr, B_, HID_, E_);
  combine_kernel<<<(B_ * HID_ + 255) / 256, 256, 0, stream>>>(
      Cpart, b1, Z, B_ * HID_, HID_, 2);

  colstats_partial_kernel<<<dim3(HID_ / 256, 16), 256, 0, stream>>>(Z, partS, partS2, B_, HID_, B_ / 16);
  colstats_final_kernel<<<HID_ / 256, 256, 0, stream>>>(partS, partS2, mean2, rstd2, HID_, 16, B_);
  bn2_apply_kernel<<<(B_ * HID_) / 256, 256, 0, stream>>>(Z, mean2, rstd2, bn2_g, bn2_b, Rbf);

  // reg_out = R @ W2^T + b2  (split-K=4: 320 blocks)
  float* reg_out = (float*)d_out;
  gemm_lds_kernel<4, false><<<dim3((NREG_ + 63) / 64, B_ / 128, 4), 256, 0, stream>>>(
      Rbf, W2_bf, nullptr, Cpart, nullptr, B_, NREG_, HID_);
  combine_kernel<<<(B_ * NREG_ + 255) / 256, 256, 0, stream>>>(
      Cpart, b2, reg_out, B_ * NREG_, NREG_, 4);

  // y_pred = softmax(reg_out @ Wc^T + bc)
  classifier_kernel<<<B_, 256, 0, stream>>>(reg_out, Wc, bc, reg_out + (size_t)B_ * NREG_);
}

// Round 6
// 455.827 us; speedup vs baseline: 1.2475x; 1.2475x over previous
//
#include <hip/hip_runtime.h>
#include <hip/hip_bf16.h>

#define B_      2048
#define R_      333
#define MAXI_   119
#define MAXO_   12
#define CONCAT_ 3325
#define E_      3328
#define TOTAL_  24696
#define HID_    1024
#define NREG_   300
#define NCLS_   180
#define EPS_    1e-5f
#define NSLOT_  128  // BN1 partial-stat slots (2048 rows / 16 rows-per-tile)
#define PSTR_   3328 // partial-stat stride

typedef __attribute__((ext_vector_type(8))) short bf16x8;
typedef __attribute__((ext_vector_type(4))) float f32x4;

static __device__ inline unsigned short f2bf_rne(float f) {
  unsigned u;
  __builtin_memcpy(&u, &f, 4);
  u += 0x7fff + ((u >> 16) & 1);     // round-nearest-even; inputs finite
  return (unsigned short)(u >> 16);
}

// ---------------- layout: ROI starts / reduced starts ----------------
__global__ void layout_kernel(int* __restrict__ starts, int* __restrict__ red_starts) {
  if (threadIdx.x == 0 && blockIdx.x == 0) {
    int s = 0, rs = 0;
    for (int r = 0; r < R_; ++r) {
      starts[r] = s;
      red_starts[r] = rs;
      s += 30 + (7 * r) % 90;
      rs += (r == 332) ? 8 : (8 + r % 5);
    }
  }
}

// ---------------- f32 -> bf16 cast (vectorized) ----------------
__global__ __launch_bounds__(256) void cast_bf16_kernel(const float* __restrict__ src,
                                                        unsigned short* __restrict__ dst, int n4) {
  int i = blockIdx.x * 256 + threadIdx.x;
  if (i >= n4) return;
  float4 v = ((const float4*)src)[i];
  ushort4 o;
  o.x = f2bf_rne(v.x); o.y = f2bf_rne(v.y); o.z = f2bf_rne(v.z); o.w = f2bf_rne(v.w);
  ((ushort4*)dst)[i] = o;
}

// ---------------- pack enc_W into MFMA A-frag order, alignment shift baked in ----------
// Wpk[r][kc][lane][8]: lane holds W'[oc=lane&15][k'=kc*32+(lane>>4)*8+e] where
// W'[oc][k'] = enc_W[r][oc][k'-s8], s8 = starts[r]&7 (zero outside [s8, s8+size)).
// y[oc,b] = sum_k' W'[oc,k'] * x[b][(start&~7)+k']  -> all x loads 16B-aligned.
__global__ __launch_bounds__(256) void pack_w_kernel(const float* __restrict__ enc_W,
                                                     const int* __restrict__ starts,
                                                     unsigned short* __restrict__ Wpk) {
  int r = blockIdx.x;
  int tid = threadIdx.x;
  int kc = tid >> 6, lane = tid & 63;
  int size = 30 + (7 * r) % 90;
  int s8 = starts[r] & 7;
  int oc = lane & 15;
  int k0 = kc * 32 + (lane >> 4) * 8;
  unsigned short o[8];
#pragma unroll
  for (int e = 0; e < 8; ++e) {
    int k = k0 + e - s8;
    float v = 0.f;
    if (oc < MAXO_ && k >= 0 && k < size) v = enc_W[((size_t)r * MAXO_ + oc) * MAXI_ + k];
    o[e] = f2bf_rne(v);
  }
  unsigned short* dst = Wpk + ((size_t)r * 4 + kc) * 512 + lane * 8;
  *(ushort4*)dst = *(ushort4*)&o[0];
  *(ushort4*)(dst + 4) = *(ushort4*)&o[4];
}

// ---------------- ragged encoder: direct global->VGPR frags, ZERO LDS / barriers ------
// grid (R_, 8); wave w of 4 handles 4 batch-tiles of 16 rows. Lane lr reads
// x[b0+lr][k0..k0+8) as two dwordx4 (16B-aligned by construction). Zero-padded
// weights absorb ragged tails; end-of-buffer frags (all-zero weight) clamp in-buffer.
__global__ __launch_bounds__(256) void encode_kernel(
    const float* __restrict__ x, const unsigned short* __restrict__ Wpk,
    const float* __restrict__ enc_b, const int* __restrict__ starts,
    const int* __restrict__ red_starts,
    float* __restrict__ yT, float* __restrict__ pS1, float* __restrict__ pS2) {
  int r  = blockIdx.x;
  int bg = blockIdx.y;                 // 0..7: rows bg*256 .. +256
  int tid = threadIdx.x;
  int wid = tid >> 6, lane = tid & 63;
  int lr = lane & 15, kg = lane >> 4;

  int size = 30 + (7 * r) % 90;
  int red  = (r == 332) ? 8 : (8 + r % 5);
  int st   = starts[r];
  int s8   = st & 7;
  int a0   = st & ~7;                  // aligned x column base
  int rs   = red_starts[r];
  int nkc  = (s8 + size + 31) >> 5;    // 1..4 K-chunks of 32
  int kmax = TOTAL_ - a0;              // multiple of 8; frags w/ nonzero weight fit

  // weights: 16 VGPRs, loaded once per wave (L2-hot, 4KB per ROI)
  bf16x8 wf[4];
  const unsigned short* wp = Wpk + (size_t)r * 2048 + lane * 8;
#pragma unroll
  for (int kc = 0; kc < 4; ++kc) wf[kc] = *(const bf16x8*)(wp + kc * 512);

  float bofs[4];
#pragma unroll
  for (int reg = 0; reg < 4; ++reg) {
    int oc = kg * 4 + reg;
    bofs[reg] = (oc < MAXO_) ? enc_b[r * MAXO_ + oc] : 0.f;
  }

  for (int t = 0; t < 4; ++t) {
    int b0 = bg * 256 + wid * 64 + t * 16;
    const float* xrow = x + (size_t)(b0 + lr) * TOTAL_ + a0;
    f32x4 acc = {0.f, 0.f, 0.f, 0.f};
#pragma unroll
    for (int kc = 0; kc < 4; ++kc) {
      if (kc < nkc) {                  // uniform per block
        int k0 = kc * 32 + kg * 8;
        if (k0 + 8 > kmax) k0 = kmax - 8;   // only all-zero-weight frags clamp
        float4 v0 = *(const float4*)(xrow + k0);
        float4 v1 = *(const float4*)(xrow + k0 + 4);
        bf16x8 xf;
        xf[0] = (short)f2bf_rne(v0.x); xf[1] = (short)f2bf_rne(v0.y);
        xf[2] = (short)f2bf_rne(v0.z); xf[3] = (short)f2bf_rne(v0.w);
        xf[4] = (short)f2bf_rne(v1.x); xf[5] = (short)f2bf_rne(v1.y);
        xf[6] = (short)f2bf_rne(v1.z); xf[7] = (short)f2bf_rne(v1.w);
        acc = __builtin_amdgcn_mfma_f32_16x16x32_bf16(wf[kc], xf, acc, 0, 0, 0);
      }
    }
    // C layout: col = lane&15 = batch, row = kg*4+reg = oc
    int slot = b0 >> 4;
#pragma unroll
    for (int reg = 0; reg < 4; ++reg) {
      int oc = kg * 4 + reg;
      if (oc < red) {
        float v = acc[reg] + bofs[reg];
        yT[(size_t)(rs + oc) * B_ + b0 + lr] = v;
        float a = v, s2 = v * v;
#pragma unroll
        for (int m = 1; m <= 8; m <<= 1) { a += __shfl_xor(a, m); s2 += __shfl_xor(s2, m); }
        if (lr == 0) {
          pS1[slot * PSTR_ + rs + oc] = a;
          pS2[slot * PSTR_ + rs + oc] = s2;
        }
      }
    }
  }
}

// ---------------- BN1 stats finalize (128 slot-partials -> mean/rstd) ----------------
__global__ __launch_bounds__(256) void bn1_stats_kernel(const float* __restrict__ pS1,
                                                        const float* __restrict__ pS2,
                                                        float* __restrict__ mean, float* __restrict__ rstd) {
  int c = blockIdx.x * 256 + threadIdx.x;
  if (c >= CONCAT_) return;
  float s = 0.f, s2 = 0.f;
  for (int i = 0; i < NSLOT_; ++i) { s += pS1[i * PSTR_ + c]; s2 += pS2[i * PSTR_ + c]; }
  float m = s / B_;
  float v = s2 / B_ - m * m;
  mean[c] = m;
  rstd[c] = rsqrtf(v + EPS_);
}

// ---------------- BN1 + LeakyReLU(0.3) + transpose + pad-col write (bf16) ----------------
__global__ __launch_bounds__(256) void bn1_transpose_kernel(
    const float* __restrict__ yT, const float* __restrict__ mean, const float* __restrict__ rstd,
    const float* __restrict__ g, const float* __restrict__ bb, unsigned short* __restrict__ Y) {
  __shared__ float tile[64][65];
  int c0 = blockIdx.x * 64, b0 = blockIdx.y * 64;
  int t = threadIdx.x;
  int bi = t & 63, ci0 = t >> 6;
  for (int ci = ci0; ci < 64; ci += 4) {
    int c = c0 + ci;
    float v = 0.f;
    if (c < CONCAT_) {
      v = (yT[(size_t)c * B_ + b0 + bi] - mean[c]) * rstd[c] * g[c] + bb[c];
      v = v > 0.f ? v : 0.3f * v;
    }
    tile[ci][bi] = v;
  }
  __syncthreads();
  int cj = t & 63, bj0 = t >> 6;
  for (int bj = bj0; bj < 64; bj += 4) {
    int c = c0 + cj;
    if (c < CONCAT_)
      Y[(size_t)(b0 + bj) * E_ + c + 1] = f2bf_rne(tile[cj][bj]);
  }
}

__global__ __launch_bounds__(256) void pad_zero_kernel(unsigned short* __restrict__ Y) {
  int i = blockIdx.x * 256 + threadIdx.x;
  if (i >= B_ * 3) return;
  int b = i / 3, which = i % 3;
  int c = (which == 0) ? 0 : ((which == 1) ? 3326 : 3327);
  Y[(size_t)b * E_ + c] = 0;
}

// ---------------- 128x64-tile dbuf bf16 MFMA GEMM (+optional split-K) ----------------
template <int KS, bool OUT_BF16>
__global__ __launch_bounds__(256) void gemm_lds_kernel(
    const unsigned short* __restrict__ A, const unsigned short* __restrict__ W,
    const float* __restrict__ bias, float* __restrict__ Cf, unsigned short* __restrict__ Cb,
    int M, int N, int K) {
  __shared__ unsigned short a_lds[2][128 * 32];
  __shared__ unsigned short b_lds[2][64 * 32];
  int tid = threadIdx.x;
  int wid = tid >> 6, lane = tid & 63;
  int wr = wid >> 1, wc = wid & 1;
  int row0 = blockIdx.y * 128, col0 = blockIdx.x * 64;
  int lr = lane & 15, kg = lane >> 4;
  int Klocal = K / KS;
  int kbase = blockIdx.z * Klocal;

  int srow = tid >> 2, sk = (tid & 3) * 8;
  const unsigned short* aptr0 = A + (size_t)(row0 + srow) * K + kbase + sk;
  const unsigned short* aptr1 = aptr0 + (size_t)64 * K;
  int bcol = col0 + srow; if (bcol > N - 1) bcol = N - 1;
  const unsigned short* bptr = W + (size_t)bcol * K + kbase + sk;

  f32x4 acc[4][2] = {};
  int nk = Klocal >> 5;

#define STAGE_(buf, kc)                                                                         \
  do {                                                                                          \
    __builtin_amdgcn_global_load_lds((const __attribute__((address_space(1))) void*)(aptr0 + (kc)), \
        (__attribute__((address_space(3))) void*)(&a_lds[buf][wid * 512]), 16, 0, 0);           \
    __builtin_amdgcn_global_load_lds((const __attribute__((address_space(1))) void*)(aptr1 + (kc)), \
        (__attribute__((address_space(3))) void*)(&a_lds[buf][2048 + wid * 512]), 16, 0, 0);    \
    __builtin_amdgcn_global_load_lds((const __attribute__((address_space(1))) void*)(bptr + (kc)),  \
        (__attribute__((address_space(3))) void*)(&b_lds[buf][wid * 512]), 16, 0, 0);           \
  } while (0)

  STAGE_(0, 0);
  __syncthreads();
  int cur = 0;
  for (int t = 0; t < nk; ++t) {
    if (t + 1 < nk) STAGE_(cur ^ 1, (t + 1) * 32);
    bf16x8 a[4], b[2];
#pragma unroll
    for (int f = 0; f < 4; ++f)
      a[f] = *(const bf16x8*)&a_lds[cur][(wr * 64 + f * 16 + lr) * 32 + kg * 8];
#pragma unroll
    for (int f = 0; f < 2; ++f)
      b[f] = *(const bf16x8*)&b_lds[cur][(wc * 32 + f * 16 + lr) * 32 + kg * 8];
#pragma unroll
    for (int i = 0; i < 4; ++i)
#pragma unroll
      for (int j = 0; j < 2; ++j)
        acc[i][j] = __builtin_amdgcn_mfma_f32_16x16x32_bf16(a[i], b[j], acc[i][j], 0, 0, 0);
    __syncthreads();
    cur ^= 1;
  }
#undef STAGE_

#pragma unroll
  for (int j = 0; j < 2; ++j) {
    int ccol = col0 + wc * 32 + j * 16 + lr;
    if (ccol >= N) continue;
    float bv = (KS == 1) ? bias[ccol] : 0.f;
#pragma unroll
    for (int i = 0; i < 4; ++i) {
#pragma unroll
      for (int reg = 0; reg < 4; ++reg) {
        int crow = row0 + wr * 64 + i * 16 + kg * 4 + reg;
        float v = acc[i][j][reg] + bv;
        if (KS == 1) {
          if (OUT_BF16) Cb[(size_t)crow * N + ccol] = f2bf_rne(v);
          else          Cf[(size_t)crow * N + ccol] = v;
        } else {
          Cf[((size_t)blockIdx.z * M + crow) * N + ccol] = v;
        }
      }
    }
  }
}

// ---------------- split-K combine: sum partials + bias ----------------
__global__ __launch_bounds__(256) void combine_kernel(
    const float* __restrict__ part, const float* __restrict__ bias,
    float* __restrict__ out, int MN, int N, int KS) {
  int i = blockIdx.x * 256 + threadIdx.x;
  if (i >= MN) return;
  float s = bias[i % N];
  for (int z = 0; z < KS; ++z) s += part[(size_t)z * MN + i];
  out[i] = s;
}

// ---------------- BN2 stats over row-major Z (two-stage, deterministic) ----------------
__global__ __launch_bounds__(256) void colstats_partial_kernel(
    const float* __restrict__ Z, float* __restrict__ pS, float* __restrict__ pS2,
    int M, int C, int rowsPerBlock) {
  int c = blockIdx.x * 256 + threadIdx.x;
  if (c >= C) return;
  int r0 = blockIdx.y * rowsPerBlock;
  float s = 0.f, s2 = 0.f;
  for (int r = r0; r < r0 + rowsPerBlock; ++r) {
    float v = Z[(size_t)r * C + c];
    s += v; s2 = fmaf(v, v, s2);
  }
  pS[blockIdx.y * C + c] = s;
  pS2[blockIdx.y * C + c] = s2;
}

__global__ __launch_bounds__(256) void colstats_final_kernel(
    const float* __restrict__ pS, const float* __restrict__ pS2,
    float* __restrict__ mean, float* __restrict__ rstd, int C, int nrb, int M) {
  int c = blockIdx.x * 256 + threadIdx.x;
  if (c >= C) return;
  float s = 0.f, s2 = 0.f;
  for (int i = 0; i < nrb; ++i) { s += pS[i * C + c]; s2 += pS2[i * C + c]; }
  float m = s / M;
  float v = s2 / M - m * m;
  mean[c] = m;
  rstd[c] = rsqrtf(v + EPS_);
}

// ---------------- BN2 apply + LeakyReLU(0.1) -> bf16 ----------------
__global__ __launch_bounds__(256) void bn2_apply_kernel(
    const float* __restrict__ Z, const float* __restrict__ mean, const float* __restrict__ rstd,
    const float* __restrict__ g, const float* __restrict__ bb, unsigned short* __restrict__ R) {
  int i = blockIdx.x * 256 + threadIdx.x;
  int c = i & (HID_ - 1);
  float v = (Z[i] - mean[c]) * rstd[c] * g[c] + bb[c];
  v = v > 0.f ? v : 0.1f * v;
  R[i] = f2bf_rne(v);
}

// ---------------- classifier: y_pred = softmax(reg @ Wc^T + bc) ----------------
__global__ __launch_bounds__(256) void classifier_kernel(
    const float* __restrict__ reg, const float* __restrict__ Wc, const float* __restrict__ bc,
    float* __restrict__ ypred) {
  int b = blockIdx.x;
  __shared__ __align__(16) float rrow[NREG_];
  __shared__ float sl[256];
  int tid = threadIdx.x;
  for (int i = tid; i < NREG_; i += 256) rrow[i] = reg[(size_t)b * NREG_ + i];
  __syncthreads();
  float s = -1e30f;
  if (tid < NCLS_) {
    const float* w = Wc + (size_t)tid * NREG_;
    float acc = 0.f;
    for (int k = 0; k < NREG_; k += 4) {
      float4 wv = *(const float4*)(w + k);
      float4 rv = *(const float4*)(&rrow[k]);
      acc = fmaf(wv.x, rv.x, acc); acc = fmaf(wv.y, rv.y, acc);
      acc = fmaf(wv.z, rv.z, acc); acc = fmaf(wv.w, rv.w, acc);
    }
    s = acc + bc[tid];
  }
  sl[tid] = s;
  __syncthreads();
  for (int o = 128; o > 0; o >>= 1) {
    if (tid < o) sl[tid] = fmaxf(sl[tid], sl[tid + o]);
    __syncthreads();
  }
  float mx = sl[0];
  __syncthreads();
  float e = (tid < NCLS_) ? __expf(s - mx) : 0.f;
  sl[tid] = e;
  __syncthreads();
  for (int o = 128; o > 0; o >>= 1) {
    if (tid < o) sl[tid] += sl[tid + o];
    __syncthreads();
  }
  if (tid < NCLS_) ypred[(size_t)b * NCLS_ + tid] = e / sl[0];
}

// ---------------- host orchestration ----------------
extern "C" void kernel_launch(void* const* d_in, const int* in_sizes, int n_in,
                              void* d_out, int out_size, void* d_ws, size_t ws_size,
                              hipStream_t stream) {
  const float* x     = (const float*)d_in[0];
  const float* enc_W = (const float*)d_in[1];
  const float* enc_b = (const float*)d_in[2];
  const float* bn1_g = (const float*)d_in[3];
  const float* bn1_b = (const float*)d_in[4];
  const float* Wqkv  = (const float*)d_in[5];
  const float* bqkv  = (const float*)d_in[6];
  const float* Wo    = (const float*)d_in[7];
  const float* bo    = (const float*)d_in[8];
  const float* W1    = (const float*)d_in[9];
  const float* b1    = (const float*)d_in[10];
  const float* bn2_g = (const float*)d_in[11];
  const float* bn2_b = (const float*)d_in[12];
  const float* W2    = (const float*)d_in[13];
  const float* b2    = (const float*)d_in[14];
  const float* Wc    = (const float*)d_in[15];
  const float* bc    = (const float*)d_in[16];

  char* ws = (char*)d_ws;
  size_t off = 0;
  auto alloc = [&](size_t bytes) -> void* {
    void* p = ws + off;
    off += (bytes + 255) & ~(size_t)255;
    return p;
  };

  float*          yT     = (float*)alloc((size_t)CONCAT_ * B_ * 4);       // reused for Z
  float*          pS1b   = (float*)alloc((size_t)NSLOT_ * PSTR_ * 4);
  float*          pS2b   = (float*)alloc((size_t)NSLOT_ * PSTR_ * 4);
  float*          mean1  = (float*)alloc(CONCAT_ * 4);
  float*          rstd1  = (float*)alloc(CONCAT_ * 4);
  unsigned short* Ybf    = (unsigned short*)alloc((size_t)B_ * E_ * 2);   // reused for O
  unsigned short* Vbf    = (unsigned short*)alloc((size_t)B_ * E_ * 2);   // reused for R
  unsigned short* Wv_bf  = (unsigned short*)alloc((size_t)E_ * E_ * 2);
  unsigned short* Wo_bf  = (unsigned short*)alloc((size_t)E_ * E_ * 2);
  unsigned short* W1_bf  = (unsigned short*)alloc((size_t)HID_ * E_ * 2);
  unsigned short* W2_bf  = (unsigned short*)alloc((size_t)NREG_ * HID_ * 2);
  unsigned short* Wpk    = (unsigned short*)alloc((size_t)R_ * 2048 * 2);
  float*          Cpart  = (float*)alloc((size_t)2 * B_ * HID_ * 4);
  float*          partS  = (float*)alloc(16 * HID_ * 4);
  float*          partS2 = (float*)alloc(16 * HID_ * 4);
  float*          mean2  = (float*)alloc(HID_ * 4);
  float*          rstd2  = (float*)alloc(HID_ * 4);
  int*            starts = (int*)alloc(R_ * 4);
  int*            redst  = (int*)alloc(R_ * 4);

  unsigned short* Obf = Ybf;
  float*          Z   = yT;
  unsigned short* Rbf = Vbf;

  layout_kernel<<<1, 1, 0, stream>>>(starts, redst);
  pack_w_kernel<<<R_, 256, 0, stream>>>(enc_W, starts, Wpk);

  int n4 = (E_ * E_) / 4;
  cast_bf16_kernel<<<(n4 + 255) / 256, 256, 0, stream>>>(Wqkv + (size_t)2 * E_ * E_, Wv_bf, n4);
  cast_bf16_kernel<<<(n4 + 255) / 256, 256, 0, stream>>>(Wo, Wo_bf, n4);
  n4 = (HID_ * E_) / 4;
  cast_bf16_kernel<<<(n4 + 255) / 256, 256, 0, stream>>>(W1, W1_bf, n4);
  n4 = (NREG_ * HID_) / 4;
  cast_bf16_kernel<<<(n4 + 255) / 256, 256, 0, stream>>>(W2, W2_bf, n4);

  encode_kernel<<<dim3(R_, 8), 256, 0, stream>>>(
      x, Wpk, enc_b, starts, redst, yT, pS1b, pS2b);
  bn1_stats_kernel<<<(CONCAT_ + 255) / 256, 256, 0, stream>>>(pS1b, pS2b, mean1, rstd1);
  bn1_transpose_kernel<<<dim3((CONCAT_ + 63) / 64, B_ / 64), 256, 0, stream>>>(
      yT, mean1, rstd1, bn1_g, bn1_b, Ybf);
  pad_zero_kernel<<<(B_ * 3 + 255) / 256, 256, 0, stream>>>(Ybf);

  // V = Y @ Wv^T + bv  (L=1 softmax == 1 -> attention output == V; q,k never needed)
  gemm_lds_kernel<1, true><<<dim3(E_ / 64, B_ / 128), 256, 0, stream>>>(
      Ybf, Wv_bf, bqkv + 2 * E_, nullptr, Vbf, B_, E_, E_);
  // O = V @ Wo^T + bo
  gemm_lds_kernel<1, true><<<dim3(E_ / 64, B_ / 128), 256, 0, stream>>>(
      Vbf, Wo_bf, bo, nullptr, Obf, B_, E_, E_);
  // Z = O @ W1^T + b1  (split-K=2: 512 blocks)
  gemm_lds_kernel<2, false><<<dim3(HID_ / 64, B_ / 128, 2), 256, 0, stream>>>(
      Obf, W1_bf, nullptr, Cpart, nullptr, B_, HID_, E_);
  combine_kernel<<<(B_ * HID_ + 255) / 256, 256, 0, stream>>>(
      Cpart, b1, Z, B_ * HID_, HID_, 2);

  colstats_partial_kernel<<<dim3(HID_ / 256, 16), 256, 0, stream>>>(Z, partS, partS2, B_, HID_, B_ / 16);
  colstats_final_kernel<<<HID_ / 256, 256, 0, stream>>>(partS, partS2, mean2, rstd2, HID_, 16, B_);
  bn2_apply_kernel<<<(B_ * HID_) / 256, 256, 0, stream>>>(Z, mean2, rstd2, bn2_g, bn2_b, Rbf);

  // reg_out = R @ W2^T + b2  (split-K=4: 320 blocks)
  float* reg_out = (float*)d_out;
  gemm_lds_kernel<4, false><<<dim3((NREG_ + 63) / 64, B_ / 128, 4), 256, 0, stream>>>(
      Rbf, W2_bf, nullptr, Cpart, nullptr, B_, NREG_, HID_);
  combine_kernel<<<(B_ * NREG_ + 255) / 256, 256, 0, stream>>>(
      Cpart, b2, reg_out, B_ * NREG_, NREG_, 4);

  // y_pred = softmax(reg_out @ Wc^T + bc)
  classifier_kernel<<<B_, 256, 0, stream>>>(reg_out, Wc, bc, reg_out + (size_t)B_ * NREG_);
}